// Round 4
// baseline (230.669 us; speedup 1.0000x reference)
//
#include <hip/hip_runtime.h>
#include <hip/hip_bf16.h>

#define D_ 1024
#define H_ 16
#define FF_ 2048
#define B_ 8
#define S_ 1027
#define MPAD_ 8320   /* 130 * 64 */
#define PSTR_ 1088   /* padded key stride for P (mult 64, covers 1027) */
#define EPS_ 1e-5f

typedef __hip_bfloat16 bf16;
typedef unsigned short u16;
typedef unsigned int u32;
typedef __attribute__((ext_vector_type(4))) float floatx4;
typedef __bf16 bf16x8 __attribute__((ext_vector_type(8)));

__device__ __forceinline__ float2 bfpair(u32 u) {
  union { u32 u; float f; } lo, hi;
  lo.u = u << 16; hi.u = u & 0xffff0000u;
  return make_float2(lo.f, hi.f);
}

__device__ __forceinline__ u32 f2bfbits(float f) {
  union { bf16 h; u16 u; } cv; cv.h = __float2bfloat16(f); return (u32)cv.u;
}

__device__ __forceinline__ float block_sum(float x, float* red) {
  const int t = threadIdx.x;
  __syncthreads();
  red[t] = x;
  __syncthreads();
  for (int s = 128; s > 0; s >>= 1) {
    if (t < s) red[t] += red[t + s];
    __syncthreads();
  }
  return red[0];
}

__device__ __forceinline__ float block_max(float x, float* red) {
  const int t = threadIdx.x;
  __syncthreads();
  red[t] = x;
  __syncthreads();
  for (int s = 128; s > 0; s >>= 1) {
    if (t < s) red[t] = fmaxf(red[t], red[t + s]);
    __syncthreads();
  }
  return red[0];
}

// Merge-source resolver: for (b, s) return src row ptr and optional add vec.
__device__ __forceinline__ void merge_src(
    int b, int s, int lx, int ly,
    const float* __restrict__ x, const float* __restrict__ y,
    const float* __restrict__ cls, const float* __restrict__ sep,
    const float* __restrict__ px, const float* __restrict__ py,
    const float*& src, const float*& add) {
  src = nullptr; add = nullptr;
  if (s == 0) src = cls;
  else if (s <= lx) { src = x + ((size_t)b * 512 + (s - 1)) * D_; add = px; }
  else if (s == lx + 1) src = sep;
  else if (s <= lx + ly + 1) { src = y + ((size_t)b * 512 + (s - lx - 2)) * D_; add = py; }
  else if (s == lx + ly + 2) src = sep;
}

// ---------------------------------------------------------------------------
// K1: fused q-projection + R-projection.
// Grid (4 col-chunks, 16 heads). Each block: q0[64] for head h (redundant
// across col-chunks), then R[c] = sum_e Wk[h*64+e][c] * q0[e], hi/lo bf16.
// ---------------------------------------------------------------------------
__global__ void __launch_bounds__(256) qr_kernel(
    const float* __restrict__ cls, const float* __restrict__ Wqkv,
    const float* __restrict__ bqkv, u16* __restrict__ RT_hi,
    u16* __restrict__ RT_lo) {
  const int cc = blockIdx.x, h = blockIdx.y, t = threadIdx.x;
  __shared__ float clds[D_];
  __shared__ float qs[64];
  *(float4*)&clds[t * 4] = ((const float4*)cls)[t];
  __syncthreads();
  const int w = t >> 6, l = t & 63;
  // q0 phase: wave w handles rows e = e8*4 + w
#pragma unroll 2
  for (int e8 = 0; e8 < 16; ++e8) {
    const int e = e8 * 4 + w;
    const float4* wr = (const float4*)(Wqkv + (size_t)(h * 64 + e) * D_) + l;
    float acc = 0.f;
#pragma unroll
    for (int c = 0; c < 4; ++c) {
      float4 wv = wr[c * 64];
      const float* cp = &clds[c * 256 + l * 4];
      acc += wv.x * cp[0] + wv.y * cp[1] + wv.z * cp[2] + wv.w * cp[3];
    }
#pragma unroll
    for (int off = 32; off > 0; off >>= 1) acc += __shfl_down(acc, off, 64);
    if (l == 0) qs[e] = (acc + bqkv[h * 64 + e]) * 0.125f;
  }
  __syncthreads();
  // R phase: col c = cc*256 + t
  const int c = cc * 256 + t;
  const float* Wk = Wqkv + (size_t)(D_ + h * 64) * D_ + c;
  float acc = 0.f;
#pragma unroll 8
  for (int e = 0; e < 64; ++e) acc += Wk[(size_t)e * D_] * qs[e];
  const u32 hb = f2bfbits(acc);
  union { u32 u; float f; } hv; hv.u = hb << 16;
  RT_hi[h * D_ + c] = (u16)hb;
  RT_lo[h * D_ + c] = (u16)f2bfbits(acc - hv.f);
}

// ---------------------------------------------------------------------------
// K2: scores S[h][m] = seq[m,:] . R[:,h] via MFMA 16x16x32 (hi+lo), reading
// x/y/cls/sep directly with inline merge (+px/py) and f32->bf16 convert.
// Grid 130 m-tiles of 64 rows; early-exit fully-invalid tiles.
// ---------------------------------------------------------------------------
__global__ void __launch_bounds__(256) scores_kernel(
    const float* __restrict__ x, const float* __restrict__ y,
    const float* __restrict__ cls, const float* __restrict__ sep,
    const float* __restrict__ px, const float* __restrict__ py,
    const int* __restrict__ x_len, const int* __restrict__ y_len,
    const u16* __restrict__ RT_hi, const u16* __restrict__ RT_lo,
    float* __restrict__ S) {
  const int m0 = blockIdx.x * 64;
  bool anyvalid = false;
#pragma unroll
  for (int b = 0; b < B_; ++b) {
    int rs = b * S_, re = rs + x_len[b] + y_len[b] + 3;
    if (m0 < re && m0 + 64 > rs) anyvalid = true;
  }
  if (!anyvalid) return;
  const int t = threadIdx.x;
  const int w = t >> 6, lane = t & 63, lane16 = lane & 15, quad = lane >> 4;
  const int row = m0 + w * 16 + lane16;
  const int b = row / S_;
  const int s = row - b * S_;
  const float* src = nullptr;
  const float* add = nullptr;
  if (b < B_) merge_src(b, s, x_len[b], y_len[b], x, y, cls, sep, px, py, src, add);
  const u16* bh = RT_hi + lane16 * D_ + quad * 8;
  const u16* bl = RT_lo + lane16 * D_ + quad * 8;
  floatx4 acc = {};
#pragma unroll 4
  for (int kt = 0; kt < 32; ++kt) {
    const int col = kt * 32 + quad * 8;
    union { bf16x8 v; u16 u[8]; } au;
    if (src) {
      float4 a0 = *(const float4*)(src + col);
      float4 a1 = *(const float4*)(src + col + 4);
      if (add) {
        float4 p0 = *(const float4*)(add + col);
        float4 p1 = *(const float4*)(add + col + 4);
        a0.x += p0.x; a0.y += p0.y; a0.z += p0.z; a0.w += p0.w;
        a1.x += p1.x; a1.y += p1.y; a1.z += p1.z; a1.w += p1.w;
      }
      au.u[0] = (u16)f2bfbits(a0.x); au.u[1] = (u16)f2bfbits(a0.y);
      au.u[2] = (u16)f2bfbits(a0.z); au.u[3] = (u16)f2bfbits(a0.w);
      au.u[4] = (u16)f2bfbits(a1.x); au.u[5] = (u16)f2bfbits(a1.y);
      au.u[6] = (u16)f2bfbits(a1.z); au.u[7] = (u16)f2bfbits(a1.w);
    } else {
#pragma unroll
      for (int j = 0; j < 8; ++j) au.u[j] = 0;
    }
    bf16x8 vh = *(const bf16x8*)(bh + kt * 32);
    bf16x8 vl = *(const bf16x8*)(bl + kt * 32);
    acc = __builtin_amdgcn_mfma_f32_16x16x32_bf16(au.v, vh, acc, 0, 0, 0);
    acc = __builtin_amdgcn_mfma_f32_16x16x32_bf16(au.v, vl, acc, 0, 0, 0);
  }
  *(floatx4*)&S[(size_t)lane16 * MPAD_ + m0 + w * 16 + quad * 4] = acc;
}

// ---------------------------------------------------------------------------
// K3: softmax per (h, b); writes normalized p as bf16, zero-padded to PSTR_.
// ---------------------------------------------------------------------------
__global__ void __launch_bounds__(256) softmax_kernel(
    const float* __restrict__ S, const int* __restrict__ x_len,
    const int* __restrict__ y_len, u16* __restrict__ P) {
  const int h = blockIdx.x, b = blockIdx.y, t = threadIdx.x;
  const int n = x_len[b] + y_len[b] + 3;
  __shared__ float sc[PSTR_];
  __shared__ float red[256];
  const float* Sp = S + (size_t)h * MPAD_ + b * S_;
  float lmax = -3.0e38f;
  for (int k = t; k < n; k += 256) {
    float s = Sp[k];
    sc[k] = s;
    lmax = fmaxf(lmax, s);
  }
  const float gmax = block_max(lmax, red);
  float lsum = 0.f;
  for (int k = t; k < n; k += 256) {
    float p = __expf(sc[k] - gmax);
    sc[k] = p;
    lsum += p;
  }
  const float inv = 1.0f / block_sum(lsum, red);
  u16* Pp = P + (size_t)(h * 8 + b) * PSTR_;
  for (int k = t; k < PSTR_; k += 256)
    Pp[k] = (k < n) ? (u16)f2bfbits(sc[k] * inv) : (u16)0;
}

// ---------------------------------------------------------------------------
// K4: cbar[b][h][c] = sum_k p[h][k] * seq[k][c] via MFMA, reading x/y directly
// with inline merge. 64-key LDS tiles, stride 70 (bank-conflict-free B-frags).
// Grid (16 coltiles, 8 b).
// ---------------------------------------------------------------------------
__global__ void __launch_bounds__(256) cbar_kernel(
    const float* __restrict__ x, const float* __restrict__ y,
    const float* __restrict__ cls, const float* __restrict__ sep,
    const float* __restrict__ px, const float* __restrict__ py,
    const int* __restrict__ x_len, const int* __restrict__ y_len,
    const u16* __restrict__ P, float* __restrict__ cbar) {
  const int ct = blockIdx.x, b = blockIdx.y, t = threadIdx.x;
  const int c0 = ct * 64;
  const int lx = x_len[b], ly = y_len[b];
  const int n = lx + ly + 3;
  const int nkt = (n + 63) >> 6;
  __shared__ u16 tile[64 * 70];
  const int w = t >> 6, lane = t & 63, lane16 = lane & 15, quad = lane >> 4;
  const int r = t >> 2;            // staged key row within tile (64)
  const int g = (t & 3) * 16;      // col group of 16 within 64
  const u16* Pp = P + (size_t)(lane16 * 8 + b) * PSTR_;
  floatx4 acc = {};
  for (int kt = 0; kt < nkt; ++kt) {
    const int k0 = kt * 64;
    __syncthreads();
    const int gk = k0 + r;
    u32 packed[8] = {};
    if (gk < n) {
      const float* src; const float* add;
      merge_src(b, gk, lx, ly, x, y, cls, sep, px, py, src, add);
      const float* sp = src + c0 + g;
#pragma unroll
      for (int q = 0; q < 4; ++q) {
        float4 v = *(const float4*)(sp + q * 4);
        if (add) {
          float4 a = *(const float4*)(add + c0 + g + q * 4);
          v.x += a.x; v.y += a.y; v.z += a.z; v.w += a.w;
        }
        packed[q * 2]     = f2bfbits(v.x) | (f2bfbits(v.y) << 16);
        packed[q * 2 + 1] = f2bfbits(v.z) | (f2bfbits(v.w) << 16);
      }
    }
#pragma unroll
    for (int q = 0; q < 8; ++q)
      *(u32*)&tile[r * 70 + g + q * 2] = packed[q];
    __syncthreads();
#pragma unroll
    for (int half = 0; half < 2; ++half) {
      const int kk = half * 32;
      bf16x8 a = *(const bf16x8*)(Pp + k0 + kk + quad * 8);
      union { bf16x8 v; u16 u[8]; } bu;
#pragma unroll
      for (int j = 0; j < 8; ++j)
        bu.u[j] = tile[(kk + quad * 8 + j) * 70 + w * 16 + lane16];
      acc = __builtin_amdgcn_mfma_f32_16x16x32_bf16(a, bu.v, acc, 0, 0, 0);
    }
  }
#pragma unroll
  for (int r4 = 0; r4 < 4; ++r4)
    cbar[(size_t)(b * 16 + quad * 4 + r4) * D_ + c0 + w * 16 + lane16] = acc[r4];
}

// ---------------------------------------------------------------------------
// Generic 8-batch GEMV: out[b][r] = in[b][:] . W[r][:] + bias[r].
// ---------------------------------------------------------------------------
template <int K, int N, int BSTR, bool INBF, bool OUTBF, bool RELU, bool PERHEAD>
__global__ void __launch_bounds__(256) gemv8_kernel(
    const void* __restrict__ in_, const float* __restrict__ W,
    const float* __restrict__ bias, void* __restrict__ out_) {
  const int t = threadIdx.x;
  const int hoff = PERHEAD ? ((blockIdx.x * 4) >> 6) * D_ : 0;
  __shared__ u16 lsb[INBF ? 8 * K : 1];
  __shared__ float lsf[INBF ? 1 : 8 * K];
  if (INBF) {
    const u16* in = (const u16*)in_;
    const int per = 8 * K / (256 * 8);
#pragma unroll
    for (int i = 0; i < per; ++i) {
      int flat = (t + i * 256) * 8;
      int b = flat / K, k = flat % K;
      *(uint4*)&lsb[flat] = *(const uint4*)(in + (size_t)b * BSTR + hoff + k);
    }
  } else {
    const float* in = (const float*)in_;
    const int per = 8 * K / (256 * 4);
#pragma unroll
    for (int i = 0; i < per; ++i) {
      int flat = (t + i * 256) * 4;
      int b = flat / K, k = flat % K;
      *(float4*)&lsf[flat] = *(const float4*)(in + (size_t)b * BSTR + hoff + k);
    }
  }
  __syncthreads();
  const int w = t >> 6, l = t & 63;
  const int r = blockIdx.x * 4 + w;
  float acc[8] = {};
#pragma unroll
  for (int ch = 0; ch < K / 256; ++ch) {
    float4 wv = *(const float4*)(W + (size_t)r * K + ch * 256 + l * 4);
#pragma unroll
    for (int b = 0; b < 8; ++b) {
      float i0, i1, i2, i3;
      if (INBF) {
        uint2 u = *(const uint2*)&lsb[b * K + ch * 256 + l * 4];
        float2 p0 = bfpair(u.x), p1 = bfpair(u.y);
        i0 = p0.x; i1 = p0.y; i2 = p1.x; i3 = p1.y;
      } else {
        const float* p = &lsf[b * K + ch * 256 + l * 4];
        i0 = p[0]; i1 = p[1]; i2 = p[2]; i3 = p[3];
      }
      acc[b] += wv.x * i0 + wv.y * i1 + wv.z * i2 + wv.w * i3;
    }
  }
#pragma unroll
  for (int off = 32; off > 0; off >>= 1)
#pragma unroll
    for (int b = 0; b < 8; ++b) acc[b] += __shfl_down(acc[b], off, 64);
  if (l == 0) {
    const float bs = bias[r];
#pragma unroll
    for (int b = 0; b < 8; ++b) {
      float v = acc[b] + bs;
      if (RELU) v = fmaxf(v, 0.f);
      if (OUTBF) ((bf16*)out_)[(size_t)b * N + r] = __float2bfloat16(v);
      else       ((float*)out_)[(size_t)b * N + r] = v;
    }
  }
}

// ---------------------------------------------------------------------------
// K7: fused LN1 + W1 GEMV + ReLU. h0 = LN(cls + att) computed in-block,
// f1[b][r] = relu(W1[r,:] . h0[b,:] + b1[r]) as bf16. Grid 512 x 4 rows.
// ---------------------------------------------------------------------------
__global__ void __launch_bounds__(256) w1ln_kernel(
    const float* __restrict__ att, const float* __restrict__ cls,
    const float* __restrict__ g1, const float* __restrict__ be1,
    const float* __restrict__ W1, const float* __restrict__ b1,
    bf16* __restrict__ f1) {
  const int t = threadIdx.x;
  __shared__ float ls[8 * D_];
  __shared__ float mn[8], rsd[8];
  float4 cv = ((const float4*)cls)[t];
#pragma unroll
  for (int i = 0; i < 8; ++i) {
    float4 a = ((const float4*)(att + (size_t)i * D_))[t];
    a.x += cv.x; a.y += cv.y; a.z += cv.z; a.w += cv.w;
    *(float4*)&ls[i * D_ + t * 4] = a;
  }
  __syncthreads();
  {
    const int b = t >> 5, j = t & 31;
    const float* base = &ls[b * D_ + j * 32];
    float s = 0.f, s2 = 0.f;
#pragma unroll
    for (int k = 0; k < 32; ++k) { float v = base[k]; s += v; s2 += v * v; }
#pragma unroll
    for (int off = 16; off > 0; off >>= 1) {
      s += __shfl_down(s, off, 32);
      s2 += __shfl_down(s2, off, 32);
    }
    if (j == 0) {
      float mean = s * (1.f / D_);
      mn[b] = mean;
      rsd[b] = rsqrtf(s2 * (1.f / D_) - mean * mean + EPS_);
    }
  }
  __syncthreads();
  {
    const int b = t >> 5, j = t & 31;
    const float mean = mn[b], rs = rsd[b];
    float* base = &ls[b * D_ + j * 32];
    const float* gp = &g1[j * 32];
    const float* bp = &be1[j * 32];
#pragma unroll
    for (int k = 0; k < 32; ++k)
      base[k] = (base[k] - mean) * rs * gp[k] + bp[k];
  }
  __syncthreads();
  const int w = t >> 6, l = t & 63;
  const int r = blockIdx.x * 4 + w;
  float acc[8] = {};
#pragma unroll
  for (int ch = 0; ch < 4; ++ch) {
    float4 wv = *(const float4*)(W1 + (size_t)r * D_ + ch * 256 + l * 4);
#pragma unroll
    for (int b = 0; b < 8; ++b) {
      const float* p = &ls[b * D_ + ch * 256 + l * 4];
      acc[b] += wv.x * p[0] + wv.y * p[1] + wv.z * p[2] + wv.w * p[3];
    }
  }
#pragma unroll
  for (int off = 32; off > 0; off >>= 1)
#pragma unroll
    for (int b = 0; b < 8; ++b) acc[b] += __shfl_down(acc[b], off, 64);
  if (l == 0) {
    const float bs = b1[r];
#pragma unroll
    for (int b = 0; b < 8; ++b)
      f1[(size_t)b * FF_ + r] = __float2bfloat16(fmaxf(acc[b] + bs, 0.f));
  }
}

// ---------------------------------------------------------------------------
// K9: final LN2. Recomputes h0 = LN1(cls + att), then out = LN2(h0 + f2).
// Grid 8 blocks (one per batch).
// ---------------------------------------------------------------------------
__global__ void __launch_bounds__(256) ln2_kernel(
    const float* __restrict__ cls, const float* __restrict__ att,
    const float* __restrict__ f2, const float* __restrict__ g1,
    const float* __restrict__ be1, const float* __restrict__ g2,
    const float* __restrict__ be2, float* __restrict__ out) {
  const int b = blockIdx.x, t = threadIdx.x;
  __shared__ float v[D_];
  __shared__ float red[256];
  for (int i = t; i < D_; i += 256) v[i] = cls[i] + att[(size_t)b * D_ + i];
  __syncthreads();
  float ls = 0.f;
  for (int i = t; i < D_; i += 256) ls += v[i];
  const float m1 = block_sum(ls, red) * (1.f / D_);
  float lv = 0.f;
  for (int i = t; i < D_; i += 256) { float dk = v[i] - m1; lv += dk * dk; }
  const float rs1 = rsqrtf(block_sum(lv, red) * (1.f / D_) + EPS_);
  __syncthreads();
  for (int i = t; i < D_; i += 256)
    v[i] = (v[i] - m1) * rs1 * g1[i] + be1[i] + f2[(size_t)b * D_ + i];
  __syncthreads();
  float ls2 = 0.f;
  for (int i = t; i < D_; i += 256) ls2 += v[i];
  const float m2 = block_sum(ls2, red) * (1.f / D_);
  float lv2 = 0.f;
  for (int i = t; i < D_; i += 256) { float dk = v[i] - m2; lv2 += dk * dk; }
  const float rs2 = rsqrtf(block_sum(lv2, red) * (1.f / D_) + EPS_);
  for (int i = t; i < D_; i += 256)
    out[(size_t)b * D_ + i] = (v[i] - m2) * rs2 * g2[i] + be2[i];
}

// ---------------------------------------------------------------------------
extern "C" void kernel_launch(void* const* d_in, const int* in_sizes, int n_in,
                              void* d_out, int out_size, void* d_ws, size_t ws_size,
                              hipStream_t stream) {
  (void)in_sizes; (void)n_in; (void)out_size; (void)ws_size;
  const float* x    = (const float*)d_in[0];
  const float* y    = (const float*)d_in[1];
  const float* cls  = (const float*)d_in[2];
  const float* sep  = (const float*)d_in[3];
  const float* px   = (const float*)d_in[4];
  const float* py   = (const float*)d_in[5];
  const float* Wqkv = (const float*)d_in[6];
  const float* bqkv = (const float*)d_in[7];
  const float* Wo   = (const float*)d_in[8];
  const float* bo   = (const float*)d_in[9];
  const float* W1   = (const float*)d_in[10];
  const float* b1   = (const float*)d_in[11];
  const float* W2   = (const float*)d_in[12];
  const float* b2   = (const float*)d_in[13];
  const float* g1   = (const float*)d_in[14];
  const float* be1  = (const float*)d_in[15];
  const float* g2   = (const float*)d_in[16];
  const float* be2  = (const float*)d_in[17];
  const int* xl     = (const int*)d_in[18];
  const int* yl     = (const int*)d_in[19];

  char* ws = (char*)d_ws;
  u16*   RT_hi = (u16*)(ws);                 //  32,768
  u16*   RT_lo = (u16*)(ws + 32768);         //  32,768
  float* S     = (float*)(ws + 65536);       // 532,480
  u16*   P     = (u16*)(ws + 598016);        // 278,528
  float* cbar  = (float*)(ws + 876544);      // 524,288
  float* o0    = (float*)(ws + 1400832);     //  32,768
  float* att   = (float*)(ws + 1433600);     //  32,768
  bf16*  f1    = (bf16*)(ws + 1466368);      //  32,768
  float* f2    = (float*)(ws + 1499136);     //  32,768

  qr_kernel<<<dim3(4, 16), 256, 0, stream>>>(cls, Wqkv, bqkv, RT_hi, RT_lo);
  scores_kernel<<<130, 256, 0, stream>>>(x, y, cls, sep, px, py, xl, yl,
                                         RT_hi, RT_lo, S);
  softmax_kernel<<<dim3(16, 8), 256, 0, stream>>>(S, xl, yl, P);
  cbar_kernel<<<dim3(16, 8), 256, 0, stream>>>(x, y, cls, sep, px, py, xl, yl,
                                               P, cbar);
  gemv8_kernel<1024, 1024, 16384, false, false, false, true>
      <<<256, 256, 0, stream>>>(cbar, Wqkv + (size_t)2048 * 1024, bqkv + 2048, o0);
  gemv8_kernel<1024, 1024, 1024, false, false, false, false>
      <<<256, 256, 0, stream>>>(o0, Wo, bo, att);
  w1ln_kernel<<<512, 256, 0, stream>>>(att, cls, g1, be1, W1, b1, f1);
  gemv8_kernel<2048, 1024, 2048, true, false, false, false>
      <<<256, 256, 0, stream>>>(f1, W2, b2, f2);
  ln2_kernel<<<B_, 256, 0, stream>>>(cls, att, f2, g1, be1, g2, be2,
                                     (float*)d_out);
}

// Round 5
// 205.934 us; speedup vs baseline: 1.1201x; 1.1201x over previous
//
#include <hip/hip_runtime.h>
#include <hip/hip_bf16.h>

#define D_ 1024
#define H_ 16
#define FF_ 2048
#define B_ 8
#define S_ 1027
#define MPAD_ 8320   /* 130 * 64 */
#define PSTR_ 1056   /* padded key stride for P (mult 32, covers 1027) */
#define EPS_ 1e-5f

typedef __hip_bfloat16 bf16;
typedef unsigned short u16;
typedef unsigned int u32;
typedef __attribute__((ext_vector_type(4))) float floatx4;
typedef __bf16 bf16x8 __attribute__((ext_vector_type(8)));

__device__ __forceinline__ float2 bfpair(u32 u) {
  union { u32 u; float f; } lo, hi;
  lo.u = u << 16; hi.u = u & 0xffff0000u;
  return make_float2(lo.f, hi.f);
}

__device__ __forceinline__ u32 f2bfbits(float f) {
  union { bf16 h; u16 u; } cv; cv.h = __float2bfloat16(f); return (u32)cv.u;
}

__device__ __forceinline__ float block_sum(float x, float* red) {
  const int t = threadIdx.x;
  __syncthreads();
  red[t] = x;
  __syncthreads();
  for (int s = 128; s > 0; s >>= 1) {
    if (t < s) red[t] += red[t + s];
    __syncthreads();
  }
  return red[0];
}

__device__ __forceinline__ float block_max(float x, float* red) {
  const int t = threadIdx.x;
  __syncthreads();
  red[t] = x;
  __syncthreads();
  for (int s = 128; s > 0; s >>= 1) {
    if (t < s) red[t] = fmaxf(red[t], red[t + s]);
    __syncthreads();
  }
  return red[0];
}

// ---------------------------------------------------------------------------
// K1: build merged sequence as bf16, coalesced (block per row). Invalid rows
// are NOT written (downstream never uses them).
// ---------------------------------------------------------------------------
__global__ void __launch_bounds__(256) build_seq_kernel(
    const float* __restrict__ x, const float* __restrict__ y,
    const float* __restrict__ cls, const float* __restrict__ sep,
    const float* __restrict__ px, const float* __restrict__ py,
    const int* __restrict__ x_len, const int* __restrict__ y_len,
    bf16* __restrict__ seq) {
  const int m = blockIdx.x, t = threadIdx.x;
  const int b = m / S_;
  const int s = m - b * S_;
  if (b >= B_) return;
  const float* src = nullptr;
  const float* add = nullptr;
  const int lx = x_len[b], ly = y_len[b];
  if (s == 0) src = cls;
  else if (s <= lx) { src = x + ((size_t)b * 512 + (s - 1)) * D_; add = px; }
  else if (s == lx + 1) src = sep;
  else if (s <= lx + ly + 1) { src = y + ((size_t)b * 512 + (s - lx - 2)) * D_; add = py; }
  else if (s == lx + ly + 2) src = sep;
  if (!src) return;
  float4 sv = ((const float4*)src)[t];
  if (add) {
    float4 av = ((const float4*)add)[t];
    sv.x += av.x; sv.y += av.y; sv.z += av.z; sv.w += av.w;
  }
  uint2 o;
  o.x = f2bfbits(sv.x) | (f2bfbits(sv.y) << 16);
  o.y = f2bfbits(sv.z) | (f2bfbits(sv.w) << 16);
  ((uint2*)(seq + (size_t)m * D_))[t] = o;
}

// ---------------------------------------------------------------------------
// K2: fused q-projection + R-projection.
// Grid (4 col-chunks, 16 heads). q0[64] recomputed per col-chunk (cheap),
// then R[c] = sum_e Wk[h*64+e][c] * q0[e], split to bf16 hi/lo.
// ---------------------------------------------------------------------------
__global__ void __launch_bounds__(256) qr_kernel(
    const float* __restrict__ cls, const float* __restrict__ Wqkv,
    const float* __restrict__ bqkv, u16* __restrict__ RT_hi,
    u16* __restrict__ RT_lo) {
  const int cc = blockIdx.x, h = blockIdx.y, t = threadIdx.x;
  __shared__ float clds[D_];
  __shared__ float qs[64];
  *(float4*)&clds[t * 4] = ((const float4*)cls)[t];
  __syncthreads();
  const int w = t >> 6, l = t & 63;
#pragma unroll 2
  for (int e8 = 0; e8 < 16; ++e8) {
    const int e = e8 * 4 + w;
    const float4* wr = (const float4*)(Wqkv + (size_t)(h * 64 + e) * D_) + l;
    float acc = 0.f;
#pragma unroll
    for (int c = 0; c < 4; ++c) {
      float4 wv = wr[c * 64];
      const float* cp = &clds[c * 256 + l * 4];
      acc += wv.x * cp[0] + wv.y * cp[1] + wv.z * cp[2] + wv.w * cp[3];
    }
#pragma unroll
    for (int off = 32; off > 0; off >>= 1) acc += __shfl_down(acc, off, 64);
    if (l == 0) qs[e] = (acc + bqkv[h * 64 + e]) * 0.125f;
  }
  __syncthreads();
  const int c = cc * 256 + t;
  const float* Wk = Wqkv + (size_t)(D_ + h * 64) * D_ + c;
  float acc = 0.f;
#pragma unroll 8
  for (int e = 0; e < 64; ++e) acc += Wk[(size_t)e * D_] * qs[e];
  const u32 hb = f2bfbits(acc);
  union { u32 u; float f; } hv; hv.u = hb << 16;
  RT_hi[h * D_ + c] = (u16)hb;
  RT_lo[h * D_ + c] = (u16)f2bfbits(acc - hv.f);
}

// ---------------------------------------------------------------------------
// K3: scores S[h][m] = seq[m,:] . R[:,h] via MFMA 16x16x32 (hi+lo).
// Grid 130 m-tiles of 64 rows; early-exit fully-invalid tiles. Fully
// unrolled K-loop so the 96 streaming loads get hoisted/pipelined.
// ---------------------------------------------------------------------------
__global__ void __launch_bounds__(256) scores_kernel(
    const bf16* __restrict__ seq, const u16* __restrict__ RT_hi,
    const u16* __restrict__ RT_lo, const int* __restrict__ x_len,
    const int* __restrict__ y_len, float* __restrict__ S) {
  const int m0 = blockIdx.x * 64;
  bool valid = false;
#pragma unroll
  for (int b = 0; b < B_; ++b) {
    int rs = b * S_, re = rs + x_len[b] + y_len[b] + 3;
    if (m0 < re && m0 + 64 > rs) valid = true;
  }
  if (!valid) return;
  const int t = threadIdx.x;
  const int w = t >> 6, lane = t & 63, lane16 = lane & 15, quad = lane >> 4;
  const int row = m0 + w * 16 + lane16;
  const u16* arow = (const u16*)seq + (size_t)row * D_ + quad * 8;
  const u16* bh = RT_hi + lane16 * D_ + quad * 8;
  const u16* bl = RT_lo + lane16 * D_ + quad * 8;
  floatx4 acc = {};
#pragma unroll
  for (int kt = 0; kt < 32; ++kt) {
    bf16x8 a  = *(const bf16x8*)(arow + kt * 32);
    bf16x8 vh = *(const bf16x8*)(bh + kt * 32);
    bf16x8 vl = *(const bf16x8*)(bl + kt * 32);
    acc = __builtin_amdgcn_mfma_f32_16x16x32_bf16(a, vh, acc, 0, 0, 0);
    acc = __builtin_amdgcn_mfma_f32_16x16x32_bf16(a, vl, acc, 0, 0, 0);
  }
  *(floatx4*)&S[(size_t)lane16 * MPAD_ + m0 + w * 16 + quad * 4] = acc;
}

// ---------------------------------------------------------------------------
// K4: softmax per (h, b); writes normalized p as bf16, zero-padded to PSTR_.
// ---------------------------------------------------------------------------
__global__ void __launch_bounds__(256) softmax_kernel(
    const float* __restrict__ S, const int* __restrict__ x_len,
    const int* __restrict__ y_len, u16* __restrict__ P) {
  const int h = blockIdx.x, b = blockIdx.y, t = threadIdx.x;
  const int n = x_len[b] + y_len[b] + 3;
  __shared__ float sc[PSTR_];
  __shared__ float red[256];
  const float* Sp = S + (size_t)h * MPAD_ + b * S_;
  float lmax = -3.0e38f;
  for (int k = t; k < n; k += 256) {
    float s = Sp[k];
    sc[k] = s;
    lmax = fmaxf(lmax, s);
  }
  const float gmax = block_max(lmax, red);
  float lsum = 0.f;
  for (int k = t; k < n; k += 256) {
    float p = __expf(sc[k] - gmax);
    sc[k] = p;
    lsum += p;
  }
  const float inv = 1.0f / block_sum(lsum, red);
  u16* Pp = P + (size_t)(h * 8 + b) * PSTR_;
  for (int k = t; k < PSTR_; k += 256)
    Pp[k] = (k < n) ? (u16)f2bfbits(sc[k] * inv) : (u16)0;
}

// ---------------------------------------------------------------------------
// K5: cbar[b][h][c] = sum_k p[h][k] * seq[bS+k][c] via MFMA (M=16 heads).
// Grid (16 coltiles x 8 b); block = 4 waves x 16 cols; K-loop tiles of 32.
// ---------------------------------------------------------------------------
__global__ void __launch_bounds__(256) cbar_kernel(
    const bf16* __restrict__ seq, const u16* __restrict__ P,
    const int* __restrict__ x_len, const int* __restrict__ y_len,
    float* __restrict__ cbar) {
  const int ct = blockIdx.x, b = blockIdx.y, t = threadIdx.x;
  const int c0 = ct * 64;
  const int n = x_len[b] + y_len[b] + 3;
  const int nkt = (n + 31) >> 5;
  __shared__ u16 tile[32 * 68];
  const int w = t >> 6, lane = t & 63, lane16 = lane & 15, quad = lane >> 4;
  const int sk = t >> 3, scg = (t & 7) * 8;   // staging: key row, col group
  floatx4 acc = {};
  for (int kt = 0; kt < nkt; ++kt) {
    const int k0 = kt * 32;
    __syncthreads();
    uint4 v = make_uint4(0u, 0u, 0u, 0u);
    if (k0 + sk < n)
      v = *(const uint4*)((const u16*)seq + (size_t)(b * S_ + k0 + sk) * D_ + c0 + scg);
    *(uint2*)&tile[sk * 68 + scg]     = make_uint2(v.x, v.y);
    *(uint2*)&tile[sk * 68 + scg + 4] = make_uint2(v.z, v.w);
    __syncthreads();
    bf16x8 a = *(const bf16x8*)(P + (size_t)(lane16 * 8 + b) * PSTR_ + k0 + quad * 8);
    union { bf16x8 v; u16 u[8]; } bu;
#pragma unroll
    for (int j = 0; j < 8; ++j)
      bu.u[j] = tile[(quad * 8 + j) * 68 + w * 16 + lane16];
    acc = __builtin_amdgcn_mfma_f32_16x16x32_bf16(a, bu.v, acc, 0, 0, 0);
  }
#pragma unroll
  for (int r = 0; r < 4; ++r)
    cbar[(size_t)(b * 16 + quad * 4 + r) * D_ + c0 + w * 16 + lane16] = acc[r];
}

// ---------------------------------------------------------------------------
// Generic 8-batch GEMV: out[b][r] = in[b][:] . W[r][:] + bias[r].
// Block = 4 waves, wave per W-row; W read once (coalesced), 8 batches reused
// from LDS. PERHEAD offsets input by (row/64)*1024 (for cbar).
// ---------------------------------------------------------------------------
template <int K, int N, int BSTR, bool INBF, bool OUTBF, bool RELU, bool PERHEAD>
__global__ void __launch_bounds__(256) gemv8_kernel(
    const void* __restrict__ in_, const float* __restrict__ W,
    const float* __restrict__ bias, void* __restrict__ out_) {
  const int t = threadIdx.x;
  const int hoff = PERHEAD ? ((blockIdx.x * 4) >> 6) * D_ : 0;
  __shared__ u16 lsb[INBF ? 8 * K : 1];
  __shared__ float lsf[INBF ? 1 : 8 * K];
  if (INBF) {
    const u16* in = (const u16*)in_;
    const int per = 8 * K / (256 * 8);
#pragma unroll
    for (int i = 0; i < per; ++i) {
      int flat = (t + i * 256) * 8;
      int b = flat / K, k = flat % K;
      *(uint4*)&lsb[flat] = *(const uint4*)(in + (size_t)b * BSTR + hoff + k);
    }
  } else {
    const float* in = (const float*)in_;
    const int per = 8 * K / (256 * 4);
#pragma unroll
    for (int i = 0; i < per; ++i) {
      int flat = (t + i * 256) * 4;
      int b = flat / K, k = flat % K;
      *(float4*)&lsf[flat] = *(const float4*)(in + (size_t)b * BSTR + hoff + k);
    }
  }
  __syncthreads();
  const int w = t >> 6, l = t & 63;
  const int r = blockIdx.x * 4 + w;
  float acc[8] = {};
#pragma unroll
  for (int ch = 0; ch < K / 256; ++ch) {
    float4 wv = *(const float4*)(W + (size_t)r * K + ch * 256 + l * 4);
#pragma unroll
    for (int b = 0; b < 8; ++b) {
      float i0, i1, i2, i3;
      if (INBF) {
        uint2 u = *(const uint2*)&lsb[b * K + ch * 256 + l * 4];
        float2 p0 = bfpair(u.x), p1 = bfpair(u.y);
        i0 = p0.x; i1 = p0.y; i2 = p1.x; i3 = p1.y;
      } else {
        const float* p = &lsf[b * K + ch * 256 + l * 4];
        i0 = p[0]; i1 = p[1]; i2 = p[2]; i3 = p[3];
      }
      acc[b] += wv.x * i0 + wv.y * i1 + wv.z * i2 + wv.w * i3;
    }
  }
#pragma unroll
  for (int off = 32; off > 0; off >>= 1)
#pragma unroll
    for (int b = 0; b < 8; ++b) acc[b] += __shfl_down(acc[b], off, 64);
  if (l == 0) {
    const float bs = bias[r];
#pragma unroll
    for (int b = 0; b < 8; ++b) {
      float v = acc[b] + bs;
      if (RELU) v = fmaxf(v, 0.f);
      if (OUTBF) ((bf16*)out_)[(size_t)b * N + r] = __float2bfloat16(v);
      else       ((float*)out_)[(size_t)b * N + r] = v;
    }
  }
}

// ---------------------------------------------------------------------------
// K8: fused LN1 + W1 GEMV + ReLU. h0 = LN(cls + att) computed in-block,
// f1[b][r] = relu(W1[r,:] . h0[b,:] + b1[r]) as bf16. Grid 512 x 4 rows.
// ---------------------------------------------------------------------------
__global__ void __launch_bounds__(256) w1ln_kernel(
    const float* __restrict__ att, const float* __restrict__ cls,
    const float* __restrict__ g1, const float* __restrict__ be1,
    const float* __restrict__ W1, const float* __restrict__ b1,
    bf16* __restrict__ f1) {
  const int t = threadIdx.x;
  __shared__ float ls[8 * D_];
  __shared__ float mn[8], rsd[8];
  float4 cv = ((const float4*)cls)[t];
#pragma unroll
  for (int i = 0; i < 8; ++i) {
    float4 a = ((const float4*)(att + (size_t)i * D_))[t];
    a.x += cv.x; a.y += cv.y; a.z += cv.z; a.w += cv.w;
    *(float4*)&ls[i * D_ + t * 4] = a;
  }
  __syncthreads();
  {
    const int b = t >> 5, j = t & 31;
    const float* base = &ls[b * D_ + j * 32];
    float s = 0.f, s2 = 0.f;
#pragma unroll
    for (int k = 0; k < 32; ++k) { float v = base[k]; s += v; s2 += v * v; }
#pragma unroll
    for (int off = 16; off > 0; off >>= 1) {
      s += __shfl_down(s, off, 32);
      s2 += __shfl_down(s2, off, 32);
    }
    if (j == 0) {
      float mean = s * (1.f / D_);
      mn[b] = mean;
      rsd[b] = rsqrtf(s2 * (1.f / D_) - mean * mean + EPS_);
    }
  }
  __syncthreads();
  {
    const int b = t >> 5, j = t & 31;
    const float mean = mn[b], rs = rsd[b];
    float* base = &ls[b * D_ + j * 32];
    const float* gp = &g1[j * 32];
    const float* bp = &be1[j * 32];
#pragma unroll
    for (int k = 0; k < 32; ++k)
      base[k] = (base[k] - mean) * rs * gp[k] + bp[k];
  }
  __syncthreads();
  const int w = t >> 6, l = t & 63;
  const int r = blockIdx.x * 4 + w;
  float acc[8] = {};
#pragma unroll
  for (int ch = 0; ch < 4; ++ch) {
    float4 wv = *(const float4*)(W1 + (size_t)r * D_ + ch * 256 + l * 4);
#pragma unroll
    for (int b = 0; b < 8; ++b) {
      const float* p = &ls[b * D_ + ch * 256 + l * 4];
      acc[b] += wv.x * p[0] + wv.y * p[1] + wv.z * p[2] + wv.w * p[3];
    }
  }
#pragma unroll
  for (int off = 32; off > 0; off >>= 1)
#pragma unroll
    for (int b = 0; b < 8; ++b) acc[b] += __shfl_down(acc[b], off, 64);
  if (l == 0) {
    const float bs = b1[r];
#pragma unroll
    for (int b = 0; b < 8; ++b)
      f1[(size_t)b * FF_ + r] = __float2bfloat16(fmaxf(acc[b] + bs, 0.f));
  }
}

// ---------------------------------------------------------------------------
// K10: final LN2. Recomputes h0 = LN1(cls + att), then out = LN2(h0 + f2).
// ---------------------------------------------------------------------------
__global__ void __launch_bounds__(256) ln2_kernel(
    const float* __restrict__ cls, const float* __restrict__ att,
    const float* __restrict__ f2, const float* __restrict__ g1,
    const float* __restrict__ be1, const float* __restrict__ g2,
    const float* __restrict__ be2, float* __restrict__ out) {
  const int b = blockIdx.x, t = threadIdx.x;
  __shared__ float v[D_];
  __shared__ float red[256];
  for (int i = t; i < D_; i += 256) v[i] = cls[i] + att[(size_t)b * D_ + i];
  __syncthreads();
  float ls = 0.f;
  for (int i = t; i < D_; i += 256) ls += v[i];
  const float m1 = block_sum(ls, red) * (1.f / D_);
  float lv = 0.f;
  for (int i = t; i < D_; i += 256) { float dk = v[i] - m1; lv += dk * dk; }
  const float rs1 = rsqrtf(block_sum(lv, red) * (1.f / D_) + EPS_);
  __syncthreads();
  for (int i = t; i < D_; i += 256)
    v[i] = (v[i] - m1) * rs1 * g1[i] + be1[i] + f2[(size_t)b * D_ + i];
  __syncthreads();
  float ls2 = 0.f;
  for (int i = t; i < D_; i += 256) ls2 += v[i];
  const float m2 = block_sum(ls2, red) * (1.f / D_);
  float lv2 = 0.f;
  for (int i = t; i < D_; i += 256) { float dk = v[i] - m2; lv2 += dk * dk; }
  const float rs2 = rsqrtf(block_sum(lv2, red) * (1.f / D_) + EPS_);
  for (int i = t; i < D_; i += 256)
    out[(size_t)b * D_ + i] = (v[i] - m2) * rs2 * g2[i] + be2[i];
}

// ---------------------------------------------------------------------------
extern "C" void kernel_launch(void* const* d_in, const int* in_sizes, int n_in,
                              void* d_out, int out_size, void* d_ws, size_t ws_size,
                              hipStream_t stream) {
  (void)in_sizes; (void)n_in; (void)out_size; (void)ws_size;
  const float* x    = (const float*)d_in[0];
  const float* y    = (const float*)d_in[1];
  const float* cls  = (const float*)d_in[2];
  const float* sep  = (const float*)d_in[3];
  const float* px   = (const float*)d_in[4];
  const float* py   = (const float*)d_in[5];
  const float* Wqkv = (const float*)d_in[6];
  const float* bqkv = (const float*)d_in[7];
  const float* Wo   = (const float*)d_in[8];
  const float* bo   = (const float*)d_in[9];
  const float* W1   = (const float*)d_in[10];
  const float* b1   = (const float*)d_in[11];
  const float* W2   = (const float*)d_in[12];
  const float* b2   = (const float*)d_in[13];
  const float* g1   = (const float*)d_in[14];
  const float* be1  = (const float*)d_in[15];
  const float* g2   = (const float*)d_in[16];
  const float* be2  = (const float*)d_in[17];
  const int* xl     = (const int*)d_in[18];
  const int* yl     = (const int*)d_in[19];

  char* ws = (char*)d_ws;
  bf16*  seq   = (bf16*)(ws);                 // 17,039,360
  u16*   RT_hi = (u16*)(ws + 17039360);       //  32,768
  u16*   RT_lo = (u16*)(ws + 17072128);       //  32,768
  float* S     = (float*)(ws + 17104896);     // 532,480
  u16*   P     = (u16*)(ws + 17637376);       // 270,336
  float* cbar  = (float*)(ws + 17907712);     // 524,288
  float* o0    = (float*)(ws + 18432000);     //  32,768
  float* att   = (float*)(ws + 18464768);     //  32,768
  bf16*  f1    = (bf16*)(ws + 18497536);      //  32,768
  float* f2    = (float*)(ws + 18530304);     //  32,768

  build_seq_kernel<<<MPAD_, 256, 0, stream>>>(x, y, cls, sep, px, py, xl, yl, seq);
  qr_kernel<<<dim3(4, 16), 256, 0, stream>>>(cls, Wqkv, bqkv, RT_hi, RT_lo);
  scores_kernel<<<130, 256, 0, stream>>>(seq, RT_hi, RT_lo, xl, yl, S);
  softmax_kernel<<<dim3(16, 8), 256, 0, stream>>>(S, xl, yl, P);
  cbar_kernel<<<dim3(16, 8), 256, 0, stream>>>(seq, P, xl, yl, cbar);
  gemv8_kernel<1024, 1024, 16384, false, false, false, true>
      <<<256, 256, 0, stream>>>(cbar, Wqkv + (size_t)2048 * 1024, bqkv + 2048, o0);
  gemv8_kernel<1024, 1024, 1024, false, false, false, false>
      <<<256, 256, 0, stream>>>(o0, Wo, bo, att);
  w1ln_kernel<<<512, 256, 0, stream>>>(att, cls, g1, be1, W1, b1, f1);
  gemv8_kernel<2048, 1024, 2048, true, false, false, false>
      <<<256, 256, 0, stream>>>(f1, W2, b2, f2);
  ln2_kernel<<<B_, 256, 0, stream>>>(cls, att, f2, g1, be1, g2, be2,
                                     (float*)d_out);
}